// Round 3
// baseline (151.368 us; speedup 1.0000x reference)
//
#include <hip/hip_runtime.h>
#include <hip/hip_bf16.h>
#include <cstdint>
#include <cstddef>

typedef __attribute__((ext_vector_type(8))) short short8;
typedef __attribute__((ext_vector_type(4))) float f32x4;

static constexpr int M_TOT = 31744;
static constexpr int N_TOT = 1152;
static constexpr int K_TOT = 768;
static constexpr long A_ELEMS = (long)M_TOT * K_TOT;   // 24379392
static constexpr long W_ELEMS = (long)N_TOT * K_TOT;   // 884736
static constexpr int CYC_ROWS = 3968;                  // one ragged cycle (4 images)

__device__ __forceinline__ unsigned short f2bf(float f) {
  unsigned int u = __float_as_uint(f);
  u += 0x7FFFu + ((u >> 16) & 1u);   // round-to-nearest-even
  return (unsigned short)(u >> 16);
}
__device__ __forceinline__ float bf2f(unsigned short u) {
  return __uint_as_float((unsigned int)u << 16);
}

// ---------------- pass 1: fp32 -> bf16 for A (seq_patches) and W ----------------
__global__ void cvt_kernel(const float* __restrict__ A, const float* __restrict__ W,
                           unsigned short* __restrict__ dst) {
  long chunk = (long)blockIdx.x * blockDim.x + threadIdx.x;  // one chunk = 8 floats
  long i = chunk * 8;
  const float* src = (i < A_ELEMS) ? (A + i) : (W + (i - A_ELEMS));
  float4 v0 = *(const float4*)(src);
  float4 v1 = *(const float4*)(src + 4);
  short8 o;
  o[0] = (short)f2bf(v0.x); o[1] = (short)f2bf(v0.y);
  o[2] = (short)f2bf(v0.z); o[3] = (short)f2bf(v0.w);
  o[4] = (short)f2bf(v1.x); o[5] = (short)f2bf(v1.y);
  o[6] = (short)f2bf(v1.z); o[7] = (short)f2bf(v1.w);
  *(short8*)(dst + i) = o;
}

// ---------------- pass 1b: pos table  tab[rem,d] = bf16(bias[d] + bilinear(pos)[rem,d]) ----
__global__ void tab_kernel(const float* __restrict__ pos, const float* __restrict__ bias,
                           unsigned short* __restrict__ tab) {
  const int t = blockIdx.x * blockDim.x + threadIdx.x;   // 571392 = 3968 * 144
  const int row = t / 144;                                // rem in [0,3968)
  const int dc = (t - row * 144) * 8;                     // d chunk base

  int rr, cc; float sy, sx;
  if (row < 1024)      { rr = row >> 5; cc = row & 31; sy = 0.5f;         sx = 0.5f; }
  else if (row < 2048) { const int li = row - 1024; rr = li >> 6; cc = li & 63; sy = 1.0f; sx = 0.25f; }
  else if (row < 3008) { const int li = row - 2048; rr = li / 40; cc = li - rr * 40; sy = 16.0f / 24.0f; sx = 0.4f; }
  else                 { const int li = row - 3008; rr = li / 24; cc = li - rr * 24; sy = 0.4f; sx = 16.0f / 24.0f; }
  float yc = fminf(fmaxf(((float)rr + 0.5f) * sy - 0.5f, 0.0f), 15.0f);
  const int y0 = (int)yc; const float fy = yc - (float)y0;
  const int y1 = y0 < 15 ? y0 + 1 : 15;
  float xc = fminf(fmaxf(((float)cc + 0.5f) * sx - 0.5f, 0.0f), 15.0f);
  const int x0 = (int)xc; const float fx = xc - (float)x0;
  const int x1 = x0 < 15 ? x0 + 1 : 15;
  const float w11 = fy * fx;
  const float w10 = fy - w11;
  const float w01 = fx - w11;
  const float w00 = 1.0f - fy - fx + w11;
  const float* p00 = pos + (size_t)(y0 * 16 + x0) * 1152 + dc;
  const float* p01 = pos + (size_t)(y0 * 16 + x1) * 1152 + dc;
  const float* p10 = pos + (size_t)(y1 * 16 + x0) * 1152 + dc;
  const float* p11 = pos + (size_t)(y1 * 16 + x1) * 1152 + dc;
  const float* bi  = bias + dc;
  short8 o;
#pragma unroll
  for (int j = 0; j < 8; ++j) {
    const float v = bi[j] + w00 * p00[j] + w01 * p01[j] + w10 * p10[j] + w11 * p11[j];
    o[j] = (short)f2bf(v);
  }
  *(short8*)(tab + (size_t)row * 1152 + dc) = o;
}

__device__ __forceinline__ void gload_lds16(const void* g, void* l) {
  __builtin_amdgcn_global_load_lds((__attribute__((address_space(1))) void*)g,
                                   (__attribute__((address_space(3))) void*)l, 16, 0, 0);
}

// ---------------- pass 2: bf16 MFMA GEMM, 3-deep pipelined, + table epilogue ----
// BM=256, BN=128, BK=64; 512 threads = 8 waves (4M x 2N), wave tile 64x64.
// LDS: 3 K-tile buffers (144 KB) -> stage tile t+2 while computing t;
// boundary wait = counted s_waitcnt vmcnt(6) (t+2's 6 loads stay in flight).
__global__ __launch_bounds__(512, 2) void gemm_kernel(
    const unsigned short* __restrict__ Abf, const unsigned short* __restrict__ Wbf,
    const unsigned short* __restrict__ tab, float* __restrict__ outp) {
  __shared__ __attribute__((aligned(16))) unsigned short As[3][256 * 64];  // 3 x 32 KB
  __shared__ __attribute__((aligned(16))) unsigned short Bs[3][128 * 64];  // 3 x 16 KB

  // bijective XCD swizzle: nwg = 1116 = 124 Mtiles * 9 Ntiles; q=139, r=4
  const int bid = blockIdx.x;
  const int xcd = bid & 7, idx = bid >> 3;
  const int wgid = (xcd < 4 ? xcd * 140 : 560 + (xcd - 4) * 139) + idx;
  const int tm = wgid / 9, tn = wgid - tm * 9;
  const int m0 = tm * 256, n0 = tn * 128;

  const int tid = threadIdx.x;
  const int w = tid >> 6, lane = tid & 63;
  const int wr = w >> 1, wc = w & 1;        // 4M x 2N waves of 64x64

  // staging address pieces (linear LDS dest, pre-swizzled global source)
  const int rowc = tid >> 3;                        // 0..63 per 64-row call
  const int chunk8 = (((tid & 7) ^ (rowc & 7)) << 3);  // element offset of 16B chunk
  const int wbase = w << 10;                        // wave-uniform LDS byte base per call

  const unsigned short* Abase = Abf + (size_t)m0 * K_TOT + chunk8 + (size_t)rowc * K_TOT;
  const unsigned short* Bbase = Wbf + (size_t)n0 * K_TOT + chunk8 + (size_t)rowc * K_TOT;

  f32x4 acc[4][4] = {};

  const int kg = lane >> 4;        // 0..3 k-group within fragment row
  const int l15 = lane & 15;

#define STAGE(tt)                                                                 \
  {                                                                               \
    const int buf_ = (tt) % 3;                                                    \
    const int k0_ = (tt) * 64;                                                    \
    char* Ab_ = (char*)As[buf_];                                                  \
    char* Bb_ = (char*)Bs[buf_];                                                  \
    gload_lds16(Abase + (size_t)0 * K_TOT + k0_,   Ab_ + 0     + wbase);          \
    gload_lds16(Abase + (size_t)64 * K_TOT + k0_,  Ab_ + 8192  + wbase);          \
    gload_lds16(Abase + (size_t)128 * K_TOT + k0_, Ab_ + 16384 + wbase);          \
    gload_lds16(Abase + (size_t)192 * K_TOT + k0_, Ab_ + 24576 + wbase);          \
    gload_lds16(Bbase + (size_t)0 * K_TOT + k0_,   Bb_ + 0     + wbase);          \
    gload_lds16(Bbase + (size_t)64 * K_TOT + k0_,  Bb_ + 8192  + wbase);          \
  }

#define COMPUTE(tt)                                                               \
  {                                                                               \
    const int buf_ = (tt) % 3;                                                    \
    const char* Ab_ = (const char*)As[buf_];                                      \
    const char* Bb_ = (const char*)Bs[buf_];                                      \
    short8 fb[4][2];                                                              \
    _Pragma("unroll") for (int n = 0; n < 4; ++n) {                               \
      const int brow = wc * 64 + n * 16 + l15;                                    \
      _Pragma("unroll") for (int kk = 0; kk < 2; ++kk)                            \
        fb[n][kk] = *(const short8*)(Bb_ + brow * 128 +                           \
                                     (((kk * 4 + kg) ^ (brow & 7)) << 4));        \
    }                                                                             \
    _Pragma("unroll") for (int mh = 0; mh < 2; ++mh) {                            \
      short8 fa[2][2];                                                            \
      _Pragma("unroll") for (int m = 0; m < 2; ++m) {                             \
        const int arow = wr * 64 + (mh * 2 + m) * 16 + l15;                       \
        _Pragma("unroll") for (int kk = 0; kk < 2; ++kk)                          \
          fa[m][kk] = *(const short8*)(Ab_ + arow * 128 +                         \
                                       (((kk * 4 + kg) ^ (arow & 7)) << 4));      \
      }                                                                           \
      _Pragma("unroll") for (int m = 0; m < 2; ++m)                               \
        _Pragma("unroll") for (int n = 0; n < 4; ++n)                             \
          _Pragma("unroll") for (int kk = 0; kk < 2; ++kk)                        \
            acc[mh * 2 + m][n] = __builtin_amdgcn_mfma_f32_16x16x32_bf16(         \
                fa[m][kk], fb[n][kk], acc[mh * 2 + m][n], 0, 0, 0);               \
    }                                                                             \
  }

  // prologue: stage tiles 0,1; wait for tile 0 (tile 1's 6 loads stay in flight)
  STAGE(0)
  STAGE(1)
  asm volatile("s_waitcnt vmcnt(6)" ::: "memory");
  __builtin_amdgcn_s_barrier();

#pragma unroll
  for (int t = 0; t < 12; ++t) {
    if (t < 10) STAGE(t + 2)
    COMPUTE(t)
    if (t < 11) {
      if (t < 10) { asm volatile("s_waitcnt vmcnt(6)" ::: "memory"); }
      else        { asm volatile("s_waitcnt vmcnt(0)" ::: "memory"); }
      __builtin_amdgcn_s_barrier();
    }
  }
#undef STAGE
#undef COMPUTE

  // ---------------- epilogue: out = acc + tab[s % 3968, d] ----------------
  const int s_base = m0 + wr * 64 + ((lane >> 4) << 2);  // + m*16 + r
  const int rem_base = s_base % CYC_ROWS;                // one div per thread
  const int d_base = n0 + wc * 64 + l15;                 // + n*16

#pragma unroll
  for (int m = 0; m < 4; ++m) {
#pragma unroll
    for (int r = 0; r < 4; ++r) {
      const int off = m * 16 + r;
      int rem = rem_base + off;
      if (rem >= CYC_ROWS) rem -= CYC_ROWS;
      const unsigned short* trow = tab + (size_t)rem * 1152 + d_base;
      float* orow = outp + (size_t)(s_base + off) * 1152 + d_base;
#pragma unroll
      for (int n = 0; n < 4; ++n)
        orow[n * 16] = acc[m][n][r] + bf2f(trow[n * 16]);
    }
  }
}

extern "C" void kernel_launch(void* const* d_in, const int* in_sizes, int n_in,
                              void* d_out, int out_size, void* d_ws, size_t ws_size,
                              hipStream_t stream) {
  const float* A    = (const float*)d_in[0];  // seq_patches [31744,768]
  const float* W    = (const float*)d_in[1];  // w [1152,768]
  const float* bias = (const float*)d_in[2];  // b [1152]
  const float* pos  = (const float*)d_in[3];  // pos_emb [256,1152]
  unsigned short* Abf = (unsigned short*)d_ws;            // 48.76 MB
  unsigned short* Wbf = Abf + A_ELEMS;                    // +1.77 MB
  unsigned short* tab = Wbf + W_ELEMS;                    // +9.14 MB (3968*1152)
  float* outp = (float*)d_out;

  cvt_kernel<<<12336, 256, 0, stream>>>(A, W, Abf);
  tab_kernel<<<2232, 256, 0, stream>>>(pos, bias, tab);
  gemm_kernel<<<1116, 512, 0, stream>>>(Abf, Wbf, tab, outp);
}

// Round 4
// 126.919 us; speedup vs baseline: 1.1926x; 1.1926x over previous
//
#include <hip/hip_runtime.h>
#include <hip/hip_bf16.h>
#include <cstdint>
#include <cstddef>

typedef __attribute__((ext_vector_type(8))) short short8;
typedef __attribute__((ext_vector_type(4))) float f32x4;

static constexpr int M_TOT = 31744;
static constexpr int N_TOT = 1152;
static constexpr int K_TOT = 768;
static constexpr long A_ELEMS = (long)M_TOT * K_TOT;   // 24379392
static constexpr long W_ELEMS = (long)N_TOT * K_TOT;   // 884736
static constexpr int CYC_ROWS = 3968;                  // one ragged cycle (4 images)

__device__ __forceinline__ unsigned short f2bf(float f) {
  unsigned int u = __float_as_uint(f);
  u += 0x7FFFu + ((u >> 16) & 1u);   // round-to-nearest-even
  return (unsigned short)(u >> 16);
}
__device__ __forceinline__ float bf2f(unsigned short u) {
  return __uint_as_float((unsigned int)u << 16);
}

// ---------------- pass 1: fp32 -> bf16 for A (seq_patches) and W ----------------
__global__ void cvt_kernel(const float* __restrict__ A, const float* __restrict__ W,
                           unsigned short* __restrict__ dst) {
  long chunk = (long)blockIdx.x * blockDim.x + threadIdx.x;  // one chunk = 8 floats
  long i = chunk * 8;
  const float* src = (i < A_ELEMS) ? (A + i) : (W + (i - A_ELEMS));
  float4 v0 = *(const float4*)(src);
  float4 v1 = *(const float4*)(src + 4);
  short8 o;
  o[0] = (short)f2bf(v0.x); o[1] = (short)f2bf(v0.y);
  o[2] = (short)f2bf(v0.z); o[3] = (short)f2bf(v0.w);
  o[4] = (short)f2bf(v1.x); o[5] = (short)f2bf(v1.y);
  o[6] = (short)f2bf(v1.z); o[7] = (short)f2bf(v1.w);
  *(short8*)(dst + i) = o;
}

// ---------------- pass 1b: pos table  tab[rem,d] = bf16(bias[d] + bilinear(pos)[rem,d]) ----
__global__ void tab_kernel(const float* __restrict__ pos, const float* __restrict__ bias,
                           unsigned short* __restrict__ tab) {
  const int t = blockIdx.x * blockDim.x + threadIdx.x;   // 571392 = 3968 * 144
  const int row = t / 144;                                // rem in [0,3968)
  const int dc = (t - row * 144) * 8;                     // d chunk base

  int rr, cc; float sy, sx;
  if (row < 1024)      { rr = row >> 5; cc = row & 31; sy = 0.5f;         sx = 0.5f; }
  else if (row < 2048) { const int li = row - 1024; rr = li >> 6; cc = li & 63; sy = 1.0f; sx = 0.25f; }
  else if (row < 3008) { const int li = row - 2048; rr = li / 40; cc = li - rr * 40; sy = 16.0f / 24.0f; sx = 0.4f; }
  else                 { const int li = row - 3008; rr = li / 24; cc = li - rr * 24; sy = 0.4f; sx = 16.0f / 24.0f; }
  float yc = fminf(fmaxf(((float)rr + 0.5f) * sy - 0.5f, 0.0f), 15.0f);
  const int y0 = (int)yc; const float fy = yc - (float)y0;
  const int y1 = y0 < 15 ? y0 + 1 : 15;
  float xc = fminf(fmaxf(((float)cc + 0.5f) * sx - 0.5f, 0.0f), 15.0f);
  const int x0 = (int)xc; const float fx = xc - (float)x0;
  const int x1 = x0 < 15 ? x0 + 1 : 15;
  const float w11 = fy * fx;
  const float w10 = fy - w11;
  const float w01 = fx - w11;
  const float w00 = 1.0f - fy - fx + w11;
  const float* p00 = pos + (size_t)(y0 * 16 + x0) * 1152 + dc;
  const float* p01 = pos + (size_t)(y0 * 16 + x1) * 1152 + dc;
  const float* p10 = pos + (size_t)(y1 * 16 + x0) * 1152 + dc;
  const float* p11 = pos + (size_t)(y1 * 16 + x1) * 1152 + dc;
  const float* bi  = bias + dc;
  short8 o;
#pragma unroll
  for (int j = 0; j < 8; ++j) {
    const float v = bi[j] + w00 * p00[j] + w01 * p01[j] + w10 * p10[j] + w11 * p11[j];
    o[j] = (short)f2bf(v);
  }
  *(short8*)(tab + (size_t)row * 1152 + dc) = o;
}

__device__ __forceinline__ void gload_lds16(const void* g, void* l) {
  __builtin_amdgcn_global_load_lds((__attribute__((address_space(1))) void*)g,
                                   (__attribute__((address_space(3))) void*)l, 16, 0, 0);
}

// ---------------- pass 2: 8-phase-style pipelined bf16 MFMA GEMM ----------------
// BM=BN=256, BK=64, 512 threads = 8 waves (2M x 4N), wave-tile 128x64.
// LDS 2x(32+32) KB double buffer. Per K-tile: 4 phases, each = {ds_read quadrant
// frags | stage one strip-unit of tile t+1 | counted vmcnt guard | barrier |
// setprio+16 MFMA | barrier}.  Units are quadrant-aligned strips so all waves
// consume in the same order; main loop never drains vmcnt to 0.
__global__ __launch_bounds__(512, 2) void gemm_kernel(
    const unsigned short* __restrict__ Abf, const unsigned short* __restrict__ Wbf,
    const unsigned short* __restrict__ tab, float* __restrict__ outp) {
  __shared__ __attribute__((aligned(16))) unsigned short As[2][256 * 64];  // 2 x 32 KB
  __shared__ __attribute__((aligned(16))) unsigned short Bs[2][256 * 64];  // 2 x 32 KB

  // grid 620 = 124 m-tiles x 5 n-tiles; bijective XCD swizzle (q=77, r=4)
  const int bid = blockIdx.x;
  const int xcd = bid & 7, idx = bid >> 3;
  const int wgid = (xcd < 4 ? xcd * 78 : 312 + (xcd - 4) * 77) + idx;
  const int tm = wgid / 5, tn = wgid - tm * 5;
  const int m0 = tm * 256, n0 = tn * 256;   // tn==4: only cols 1024..1151 valid

  const int tid = threadIdx.x;
  const int w = tid >> 6, lane = tid & 63;
  const int wm = w >> 2, wn = w & 3;        // 2M x 4N waves, wave-tile 128x64
  const int lr = lane >> 3;                 // 0..7
  const int csw = ((lane & 7) ^ lr) << 3;   // pre-swizzled source chunk (elems)
  const int kg = lane >> 4, l15 = lane & 15;

  // A staging: per-lane global base (row m0 + w*8 + lr), wave-uniform LDS base w*1KB
  const unsigned short* Ab0 = Abf + (size_t)(m0 + w * 8 + lr) * K_TOT + csw;
  const int a_wu = w << 10;
  // B staging: strip rows; wave half-select and lane row within strip
  const int brow_lane = (w & 3) * 8 + lr;   // 0..31 within a 32-row strip
  const int b_ws = (w >> 2) * 64;           // strip-half offset (0 or 64)
  const int b_wu = (w & 3) << 10;

  f32x4 acc[8][4] = {};
  short8 fa[4][2];
  short8 fb[2][2][2];

#define STAGE_A(p, t1, H)                                                        \
  { gload_lds16(Ab0 + (size_t)((H) * 64) * K_TOT + (t1) * 64,                    \
                (char*)As[p] + ((H) * 64) * 128 + a_wu);                         \
    gload_lds16(Ab0 + (size_t)((H) * 64 + 128) * K_TOT + (t1) * 64,              \
                (char*)As[p] + ((H) * 64 + 128) * 128 + a_wu); }

#define STAGE_B(p, t1, NQ)                                                       \
  { const int sb0_ = (NQ) * 32 + b_ws;                                           \
    int br0_ = n0 + sb0_ + brow_lane; if (br0_ > N_TOT - 1) br0_ = N_TOT - 1;    \
    gload_lds16(Wbf + (size_t)br0_ * K_TOT + csw + (t1) * 64,                    \
                (char*)Bs[p] + sb0_ * 128 + b_wu);                               \
    const int sb1_ = sb0_ + 128;                                                 \
    int br1_ = n0 + sb1_ + brow_lane; if (br1_ > N_TOT - 1) br1_ = N_TOT - 1;    \
    gload_lds16(Wbf + (size_t)br1_ * K_TOT + csw + (t1) * 64,                    \
                (char*)Bs[p] + sb1_ * 128 + b_wu); }

#define LOAD_FA(p, MQ)                                                           \
  _Pragma("unroll") for (int j = 0; j < 4; ++j) {                                \
    const int ar_ = wm * 128 + (MQ) * 64 + j * 16 + l15;                         \
    const char* ba_ = (const char*)As[p] + ar_ * 128;                            \
    fa[j][0] = *(const short8*)(ba_ + ((kg ^ (ar_ & 7)) << 4));                  \
    fa[j][1] = *(const short8*)(ba_ + (((4 + kg) ^ (ar_ & 7)) << 4));            \
  }

#define LOAD_FB(p, NQ)                                                           \
  _Pragma("unroll") for (int j = 0; j < 2; ++j) {                                \
    const int br_ = wn * 64 + (NQ) * 32 + j * 16 + l15;                          \
    const char* bb_ = (const char*)Bs[p] + br_ * 128;                            \
    fb[NQ][j][0] = *(const short8*)(bb_ + ((kg ^ (br_ & 7)) << 4));              \
    fb[NQ][j][1] = *(const short8*)(bb_ + (((4 + kg) ^ (br_ & 7)) << 4));        \
  }

#define MFMA_Q(MQ, NQ)                                                           \
  _Pragma("unroll") for (int j = 0; j < 4; ++j)                                  \
    _Pragma("unroll") for (int jj = 0; jj < 2; ++jj) {                           \
      acc[(MQ) * 4 + j][(NQ) * 2 + jj] = __builtin_amdgcn_mfma_f32_16x16x32_bf16(\
          fa[j][0], fb[NQ][jj][0], acc[(MQ) * 4 + j][(NQ) * 2 + jj], 0, 0, 0);   \
      acc[(MQ) * 4 + j][(NQ) * 2 + jj] = __builtin_amdgcn_mfma_f32_16x16x32_bf16(\
          fa[j][1], fb[NQ][jj][1], acc[(MQ) * 4 + j][(NQ) * 2 + jj], 0, 0, 0);   \
    }

#define BAR __builtin_amdgcn_s_barrier()
#define SP1 __builtin_amdgcn_s_setprio(1)
#define SP0 __builtin_amdgcn_s_setprio(0)
#define VM4 asm volatile("s_waitcnt vmcnt(4)" ::: "memory")
#define VM2 asm volatile("s_waitcnt vmcnt(2)" ::: "memory")
#define VM0 asm volatile("s_waitcnt vmcnt(0)" ::: "memory")

  // prologue: stage tile 0 in unit order (A0, B0, B1, A1); wait for A0+B0.
  STAGE_A(0, 0, 0)
  STAGE_B(0, 0, 0)
  STAGE_B(0, 0, 1)
  STAGE_A(0, 0, 1)
  VM4;
  BAR;

#pragma unroll
  for (int t = 0; t < 11; ++t) {
    const int p = t & 1, q = p ^ 1;
    // phase 1: quadrant (0,0); stage (t+1).A0; guard t.B1 for ph2
    LOAD_FA(p, 0) LOAD_FB(p, 0)
    STAGE_A(q, t + 1, 0)
    VM4; BAR; SP1; MFMA_Q(0, 0) SP0; BAR;
    // phase 2: quadrant (0,1); stage (t+1).B0; guard t.A1 for ph3
    LOAD_FB(p, 1)
    STAGE_B(q, t + 1, 0)
    VM4; BAR; SP1; MFMA_Q(0, 1) SP0; BAR;
    // phase 3: quadrant (1,0); stage (t+1).B1; no guard
    LOAD_FA(p, 1)
    STAGE_B(q, t + 1, 1)
    BAR; SP1; MFMA_Q(1, 0) SP0; BAR;
    // phase 4: quadrant (1,1); stage (t+1).A1; guard (t+1).A0+B0 for next ph1
    STAGE_A(q, t + 1, 1)
    VM4; BAR; SP1; MFMA_Q(1, 1) SP0; BAR;
    __builtin_amdgcn_sched_barrier(0);   // pin tile boundary (cross-wave hazard)
  }

  // t = 11 (last tile, buf 1): no staging; drain progressively
  LOAD_FA(1, 0) LOAD_FB(1, 0)
  VM2; BAR; SP1; MFMA_Q(0, 0) SP0; BAR;
  LOAD_FB(1, 1)
  VM0; BAR; SP1; MFMA_Q(0, 1) SP0; BAR;
  LOAD_FA(1, 1)
  BAR; SP1; MFMA_Q(1, 0) SP0; BAR;
  SP1; MFMA_Q(1, 1) SP0;

#undef STAGE_A
#undef STAGE_B
#undef LOAD_FA
#undef LOAD_FB
#undef MFMA_Q

  // ---------------- epilogue: out = acc + tab[s % 3968, d] ----------------
  const int s_base = m0 + wm * 128 + ((lane >> 4) << 2);
  const int rem_base = s_base % CYC_ROWS;
  const int d_base = n0 + wn * 64 + l15;
  if (n0 + wn * 64 < N_TOT) {   // wave-uniform tail mask (tn==4, wn>=2 skip)
#pragma unroll
    for (int fm = 0; fm < 8; ++fm) {
#pragma unroll
      for (int r = 0; r < 4; ++r) {
        const int off = fm * 16 + r;
        int rem = rem_base + off;
        if (rem >= CYC_ROWS) rem -= CYC_ROWS;
        const unsigned short* trow = tab + (size_t)rem * 1152 + d_base;
        float* orow = outp + (size_t)(s_base + off) * 1152 + d_base;
#pragma unroll
        for (int fn = 0; fn < 4; ++fn)
          orow[fn * 16] = acc[fm][fn][r] + bf2f(trow[fn * 16]);
      }
    }
  }
}

extern "C" void kernel_launch(void* const* d_in, const int* in_sizes, int n_in,
                              void* d_out, int out_size, void* d_ws, size_t ws_size,
                              hipStream_t stream) {
  const float* A    = (const float*)d_in[0];  // seq_patches [31744,768]
  const float* W    = (const float*)d_in[1];  // w [1152,768]
  const float* bias = (const float*)d_in[2];  // b [1152]
  const float* pos  = (const float*)d_in[3];  // pos_emb [256,1152]
  unsigned short* Abf = (unsigned short*)d_ws;            // 48.76 MB
  unsigned short* Wbf = Abf + A_ELEMS;                    // +1.77 MB
  unsigned short* tab = Wbf + W_ELEMS;                    // +9.14 MB (3968*1152)
  float* outp = (float*)d_out;

  cvt_kernel<<<12336, 256, 0, stream>>>(A, W, Abf);
  tab_kernel<<<2232, 256, 0, stream>>>(pos, bias, tab);
  gemm_kernel<<<620, 512, 0, stream>>>(Abf, Wbf, tab, outp);
}

// Round 5
// 117.993 us; speedup vs baseline: 1.2829x; 1.0756x over previous
//
#include <hip/hip_runtime.h>
#include <hip/hip_bf16.h>
#include <cstdint>
#include <cstddef>

typedef __attribute__((ext_vector_type(8))) short short8;
typedef __attribute__((ext_vector_type(4))) float f32x4;

static constexpr int M_TOT = 31744;
static constexpr int N_TOT = 1152;
static constexpr int K_TOT = 768;
static constexpr long A_ELEMS = (long)M_TOT * K_TOT;   // 24379392
static constexpr long W_ELEMS = (long)N_TOT * K_TOT;   // 884736
static constexpr int CYC_ROWS = 3968;                  // one ragged cycle (4 images)

__device__ __forceinline__ unsigned short f2bf(float f) {
  unsigned int u = __float_as_uint(f);
  u += 0x7FFFu + ((u >> 16) & 1u);   // round-to-nearest-even
  return (unsigned short)(u >> 16);
}
__device__ __forceinline__ float bf2f(unsigned short u) {
  return __uint_as_float((unsigned int)u << 16);
}

// ---------------- pass 1: fp32 -> bf16 for A (seq_patches) and W ----------------
__global__ void cvt_kernel(const float* __restrict__ A, const float* __restrict__ W,
                           unsigned short* __restrict__ dst) {
  long chunk = (long)blockIdx.x * blockDim.x + threadIdx.x;  // one chunk = 8 floats
  long i = chunk * 8;
  const float* src = (i < A_ELEMS) ? (A + i) : (W + (i - A_ELEMS));
  float4 v0 = *(const float4*)(src);
  float4 v1 = *(const float4*)(src + 4);
  short8 o;
  o[0] = (short)f2bf(v0.x); o[1] = (short)f2bf(v0.y);
  o[2] = (short)f2bf(v0.z); o[3] = (short)f2bf(v0.w);
  o[4] = (short)f2bf(v1.x); o[5] = (short)f2bf(v1.y);
  o[6] = (short)f2bf(v1.z); o[7] = (short)f2bf(v1.w);
  *(short8*)(dst + i) = o;
}

// ---------------- pass 1b: pos table  tab[rem,d] = bf16(bias[d] + bilinear(pos)[rem,d]) ----
__global__ void tab_kernel(const float* __restrict__ pos, const float* __restrict__ bias,
                           unsigned short* __restrict__ tab) {
  const int t = blockIdx.x * blockDim.x + threadIdx.x;   // 571392 = 3968 * 144
  const int row = t / 144;                                // rem in [0,3968)
  const int dc = (t - row * 144) * 8;                     // d chunk base

  int rr, cc; float sy, sx;
  if (row < 1024)      { rr = row >> 5; cc = row & 31; sy = 0.5f;         sx = 0.5f; }
  else if (row < 2048) { const int li = row - 1024; rr = li >> 6; cc = li & 63; sy = 1.0f; sx = 0.25f; }
  else if (row < 3008) { const int li = row - 2048; rr = li / 40; cc = li - rr * 40; sy = 16.0f / 24.0f; sx = 0.4f; }
  else                 { const int li = row - 3008; rr = li / 24; cc = li - rr * 24; sy = 0.4f; sx = 16.0f / 24.0f; }
  float yc = fminf(fmaxf(((float)rr + 0.5f) * sy - 0.5f, 0.0f), 15.0f);
  const int y0 = (int)yc; const float fy = yc - (float)y0;
  const int y1 = y0 < 15 ? y0 + 1 : 15;
  float xc = fminf(fmaxf(((float)cc + 0.5f) * sx - 0.5f, 0.0f), 15.0f);
  const int x0 = (int)xc; const float fx = xc - (float)x0;
  const int x1 = x0 < 15 ? x0 + 1 : 15;
  const float w11 = fy * fx;
  const float w10 = fy - w11;
  const float w01 = fx - w11;
  const float w00 = 1.0f - fy - fx + w11;
  const float* p00 = pos + (size_t)(y0 * 16 + x0) * 1152 + dc;
  const float* p01 = pos + (size_t)(y0 * 16 + x1) * 1152 + dc;
  const float* p10 = pos + (size_t)(y1 * 16 + x0) * 1152 + dc;
  const float* p11 = pos + (size_t)(y1 * 16 + x1) * 1152 + dc;
  const float* bi  = bias + dc;
  short8 o;
#pragma unroll
  for (int j = 0; j < 8; ++j) {
    const float v = bi[j] + w00 * p00[j] + w01 * p01[j] + w10 * p10[j] + w11 * p11[j];
    o[j] = (short)f2bf(v);
  }
  *(short8*)(tab + (size_t)row * 1152 + dc) = o;
}

__device__ __forceinline__ void gload_lds16(const void* g, void* l) {
  __builtin_amdgcn_global_load_lds((__attribute__((address_space(1))) void*)g,
                                   (__attribute__((address_space(3))) void*)l, 16, 0, 0);
}

// ---------------- pass 2: bf16 MFMA GEMM, 2-phase double-buffered (T3-min) ----------
// 128x128 tile, BK=64, 256 threads = 4 waves (2x2), wave-tile 64x64.
// Per K-tile: STAGE(t+1 -> buf q) issued BEFORE compute(buf p); one
// vmcnt(0)+barrier per tile (after compute) — stage latency hides under MFMA.
// LDS 2x32 KB = 64 KB -> 2 blocks/CU co-resident for cross-block overlap.
__global__ __launch_bounds__(256) void gemm_kernel(
    const unsigned short* __restrict__ Abf, const unsigned short* __restrict__ Wbf,
    const unsigned short* __restrict__ tab, float* __restrict__ outp) {
  __shared__ __attribute__((aligned(16))) unsigned short As[2][128 * 64];  // 2 x 16 KB
  __shared__ __attribute__((aligned(16))) unsigned short Bs[2][128 * 64];  // 2 x 16 KB

  // XCD-bijective swizzle: 2232 tiles = 8 XCDs * 279.  Same-M panels stay on one XCD.
  const int bid = blockIdx.x;
  const int tile = (bid & 7) * 279 + (bid >> 3);
  const int tm = tile / 9, tn = tile % 9;   // 248 x 9 tiles of 128x128
  const int m0 = tm * 128, n0 = tn * 128;

  const int tid = threadIdx.x;
  const int wid = tid >> 6, lane = tid & 63;
  const int wr = wid >> 1, wc = wid & 1;    // 2x2 waves, 64x64 each
  const int rb = wid * 32;                  // this wave's staging row base
  const int lrow = lane >> 3;               // 0..7 rows per 1KB wave-call
  const int lcol = ((lane & 7) ^ lrow) * 8; // pre-swizzled source chunk (elements)
  const int kg = lane >> 4, l15 = lane & 15;

  f32x4 acc[4][4] = {};

  const unsigned short* Abase = Abf + (size_t)m0 * K_TOT;
  const unsigned short* Bbase = Wbf + (size_t)n0 * K_TOT;

#define STAGE(p, kt)                                                             \
  { const int k0_ = (kt) * 64;                                                   \
    _Pragma("unroll") for (int c = 0; c < 4; ++c) {                              \
      const int row_ = rb + c * 8;                                               \
      gload_lds16(Abase + (size_t)(row_ + lrow) * K_TOT + k0_ + lcol,            \
                  (char*)As[p] + row_ * 128);                                    \
      gload_lds16(Bbase + (size_t)(row_ + lrow) * K_TOT + k0_ + lcol,            \
                  (char*)Bs[p] + row_ * 128);                                    \
    } }

#define COMPUTE(p)                                                               \
  { __builtin_amdgcn_s_setprio(1);                                               \
    _Pragma("unroll") for (int kk = 0; kk < 2; ++kk) {                           \
      short8 fa[4], fb[4];                                                       \
      _Pragma("unroll") for (int m = 0; m < 4; ++m) {                            \
        const int arow = wr * 64 + m * 16 + l15;                                 \
        fa[m] = *(const short8*)((const char*)As[p] + arow * 128 +               \
                                 (((kk * 4 + kg) ^ (arow & 7)) << 4));           \
      }                                                                          \
      _Pragma("unroll") for (int n = 0; n < 4; ++n) {                            \
        const int brow = wc * 64 + n * 16 + l15;                                 \
        fb[n] = *(const short8*)((const char*)Bs[p] + brow * 128 +               \
                                 (((kk * 4 + kg) ^ (brow & 7)) << 4));           \
      }                                                                          \
      _Pragma("unroll") for (int m = 0; m < 4; ++m)                              \
        _Pragma("unroll") for (int n = 0; n < 4; ++n)                            \
          acc[m][n] = __builtin_amdgcn_mfma_f32_16x16x32_bf16(                   \
              fa[m], fb[n], acc[m][n], 0, 0, 0);                                 \
    }                                                                            \
    __builtin_amdgcn_s_setprio(0); }

  // prologue: stage tile 0, full drain, barrier
  STAGE(0, 0)
  asm volatile("s_waitcnt vmcnt(0)" ::: "memory");
  __builtin_amdgcn_s_barrier();

  // main loop: stage t+1 into q BEFORE computing p; one drain+barrier per tile.
  // vmcnt(0) after compute only exposes (stage latency - compute time) ~ 0.
#pragma unroll
  for (int t = 0; t < 11; ++t) {
    const int p = t & 1, q = p ^ 1;
    STAGE(q, t + 1)
    COMPUTE(p)
    asm volatile("s_waitcnt vmcnt(0)" ::: "memory");
    __builtin_amdgcn_s_barrier();
  }
  COMPUTE(1)   // tile 11 resides in buf 1

#undef STAGE
#undef COMPUTE

  // ---------------- epilogue: out = acc + tab[s % 3968, d] ----------------
  const int s_base = m0 + wr * 64 + ((lane >> 4) << 2);  // + m*16 + r
  const int rem_base = s_base % CYC_ROWS;                // one div per thread
  const int d_base = n0 + wc * 64 + l15;                 // + n*16

#pragma unroll
  for (int m = 0; m < 4; ++m) {
#pragma unroll
    for (int r = 0; r < 4; ++r) {
      const int off = m * 16 + r;
      int rem = rem_base + off;
      if (rem >= CYC_ROWS) rem -= CYC_ROWS;
      const unsigned short* trow = tab + (size_t)rem * 1152 + d_base;
      float* orow = outp + (size_t)(s_base + off) * 1152 + d_base;
#pragma unroll
      for (int n = 0; n < 4; ++n)
        orow[n * 16] = acc[m][n][r] + bf2f(trow[n * 16]);
    }
  }
}

extern "C" void kernel_launch(void* const* d_in, const int* in_sizes, int n_in,
                              void* d_out, int out_size, void* d_ws, size_t ws_size,
                              hipStream_t stream) {
  const float* A    = (const float*)d_in[0];  // seq_patches [31744,768]
  const float* W    = (const float*)d_in[1];  // w [1152,768]
  const float* bias = (const float*)d_in[2];  // b [1152]
  const float* pos  = (const float*)d_in[3];  // pos_emb [256,1152]
  unsigned short* Abf = (unsigned short*)d_ws;            // 48.76 MB
  unsigned short* Wbf = Abf + A_ELEMS;                    // +1.77 MB
  unsigned short* tab = Wbf + W_ELEMS;                    // +9.14 MB (3968*1152)
  float* outp = (float*)d_out;

  cvt_kernel<<<12336, 256, 0, stream>>>(A, W, Abf);
  tab_kernel<<<2232, 256, 0, stream>>>(pos, bias, tab);
  gemm_kernel<<<2232, 256, 0, stream>>>(Abf, Wbf, tab, outp);
}